// Round 1
// baseline (104.343 us; speedup 1.0000x reference)
//
#include <hip/hip_runtime.h>

// SGCN fused: out[n,d,t,w] = sum_v (sum_c x[n,c,t,v]*W[c,d] + b[d]) * a[n,t,v,w]
// plus exact f32 copy of a into d_out second region.
// N=64, C_IN=C_OUT=64, T=300, V=25.

typedef __attribute__((ext_vector_type(8))) short short8;
typedef __attribute__((ext_vector_type(4))) float f32x4;

#define XS_S 72   // Xs/Wt row stride in ushort (144B, 16B-aligned, conflict-minimal)
#define YS_S 40   // Ys row stride (80B)
#define AT_S 40   // At row stride (80B)

__device__ __forceinline__ unsigned short f2bf(float f) {
    // RNE float->bf16 (finite inputs)
    unsigned int u = __builtin_bit_cast(unsigned int, f);
    return (unsigned short)((u + 0x7FFFu + ((u >> 16) & 1u)) >> 16);
}

__global__ __launch_bounds__(256, 2)
void sgcn_fused(const float* __restrict__ xg, const float* __restrict__ ag,
                const float* __restrict__ Wg, const float* __restrict__ bg,
                float* __restrict__ outg)
{
    __shared__ alignas(16) unsigned short Wt[64 * XS_S];      // W^T as [d][c]
    __shared__ alignas(16) unsigned short Xs[4][32 * XS_S];   // per-wave x-slice [v][c]
    __shared__ alignas(16) unsigned short Ys[4][64 * YS_S];   // per-wave y [d][v]
    __shared__ alignas(16) unsigned short At[4][32 * AT_S];   // per-wave a-slice [w][v]

    const int tid  = threadIdx.x;
    const int wid  = tid >> 6;
    const int lane = tid & 63;
    const int q    = lane >> 4;   // 0..3
    const int lo   = lane & 15;   // 0..15

    const int bid = blockIdx.x;
    const int n   = bid / 25;
    const int t0  = (bid % 25) * 12;

    // ---- zero LDS (pad columns v>=25 must be 0 for the K-dim of step 2) ----
    {
        unsigned int* zx = (unsigned int*)&Xs[0][0];
        for (int i = tid; i < 4 * 32 * XS_S / 2; i += 256) zx[i] = 0u;
        unsigned int* zy = (unsigned int*)&Ys[0][0];
        for (int i = tid; i < 4 * 64 * YS_S / 2; i += 256) zy[i] = 0u;
        unsigned int* za = (unsigned int*)&At[0][0];
        for (int i = tid; i < 4 * 32 * AT_S / 2; i += 256) za[i] = 0u;
    }
    // ---- stage W transposed (once per block) ----
    for (int i = tid; i < 4096; i += 256) {
        const int c = i >> 6, d = i & 63;
        Wt[d * XS_S + c] = f2bf(Wg[i]);   // Wg is [c][d]
    }
    __syncthreads();

    // ---- per-wave: hoist W A-fragments and bias into registers ----
    // A-frag (16x16x32): lane holds A[row=lo][k = 8*q + i], i=0..7
    short8 wfrag[4][2];
#pragma unroll
    for (int mi = 0; mi < 4; ++mi)
#pragma unroll
        for (int ki = 0; ki < 2; ++ki)
            wfrag[mi][ki] = *(const short8*)&Wt[(16 * mi + lo) * XS_S + 32 * ki + 8 * q];

    f32x4 bias[4];
#pragma unroll
    for (int mi = 0; mi < 4; ++mi)
#pragma unroll
        for (int r = 0; r < 4; ++r)
            bias[mi][r] = bg[16 * mi + 4 * q + r];

    unsigned short* xs = Xs[wid];
    unsigned short* ys = Ys[wid];
    unsigned short* at = At[wid];
    const long aoff = 30720000L;   // out region size (N*COUT*T*V)

    for (int k = 0; k < 3; ++k) {
        const int t = t0 + 4 * k + wid;   // each wave owns one t

        // ---- stage x[n, c=lane, t, 0:25] -> Xs[v][c] (bf16, transposed) ----
        const float* xp = xg + (((long)n * 64 + lane) * 300 + t) * 25;
#pragma unroll
        for (int v = 0; v < 25; ++v)
            xs[v * XS_S + lane] = f2bf(xp[v]);

        // ---- stage a[n,t] -> At[w][v] (transposed) + exact f32 copy to out ----
        const float* ap = ag + ((long)n * 300 + t) * 625;
        float* ao = outg + aoff + ((long)n * 300 + t) * 625;
#pragma unroll
        for (int j = 0; j < 10; ++j) {
            const int el = lane + 64 * j;
            if (el < 625) {
                const float av = ap[el];
                ao[el] = av;
                at[(el % 25) * AT_S + (el / 25)] = f2bf(av);
            }
        }

        // ---- step 1: y[d,v] = b[d] + sum_c W[c,d] x[c,v]  (M=64,N=32pad,K=64) ----
        f32x4 accy[4][2];
#pragma unroll
        for (int mi = 0; mi < 4; ++mi) { accy[mi][0] = bias[mi]; accy[mi][1] = bias[mi]; }
#pragma unroll
        for (int ni = 0; ni < 2; ++ni)
#pragma unroll
            for (int ki = 0; ki < 2; ++ki) {
                // B-frag: lane holds B[k=8q+i][col=lo] = x[c=32ki+8q+i][v=16ni+lo]
                const short8 bf = *(const short8*)&xs[(16 * ni + lo) * XS_S + 32 * ki + 8 * q];
#pragma unroll
                for (int mi = 0; mi < 4; ++mi)
                    accy[mi][ni] = __builtin_amdgcn_mfma_f32_16x16x32_bf16(
                        wfrag[mi][ki], bf, accy[mi][ni], 0, 0, 0);
            }

        // ---- y -> Ys[d][v] (bf16), mask v<25 so pad stays zero ----
        // C/D layout: lane holds D[row=4q+r][col=lo]
#pragma unroll
        for (int mi = 0; mi < 4; ++mi)
#pragma unroll
            for (int ni = 0; ni < 2; ++ni) {
                const int v = 16 * ni + lo;
                if (v < 25) {
#pragma unroll
                    for (int r = 0; r < 4; ++r)
                        ys[(16 * mi + 4 * q + r) * YS_S + v] = f2bf(accy[mi][ni][r]);
                }
            }

        // ---- step 2: out[d,w] = sum_v y[d,v] a[v,w]  (M=64,N=32pad,K=32pad) ----
        f32x4 acco[4][2];
#pragma unroll
        for (int mi = 0; mi < 4; ++mi) {
            acco[mi][0] = f32x4{0.f, 0.f, 0.f, 0.f};
            acco[mi][1] = f32x4{0.f, 0.f, 0.f, 0.f};
        }
        short8 afr[4];
#pragma unroll
        for (int mi = 0; mi < 4; ++mi)
            afr[mi] = *(const short8*)&ys[(16 * mi + lo) * YS_S + 8 * q];
#pragma unroll
        for (int ni = 0; ni < 2; ++ni) {
            const short8 bfr = *(const short8*)&at[(16 * ni + lo) * AT_S + 8 * q];
#pragma unroll
            for (int mi = 0; mi < 4; ++mi)
                acco[mi][ni] = __builtin_amdgcn_mfma_f32_16x16x32_bf16(
                    afr[mi], bfr, acco[mi][ni], 0, 0, 0);
        }

        // ---- store out[n, d, t, w] (f32), mask w<25 ----
        float* op = outg + (((long)n * 64) * 300 + t) * 25;
#pragma unroll
        for (int mi = 0; mi < 4; ++mi)
#pragma unroll
            for (int ni = 0; ni < 2; ++ni) {
                const int w = 16 * ni + lo;
                if (w < 25) {
#pragma unroll
                    for (int r = 0; r < 4; ++r) {
                        const int d = 16 * mi + 4 * q + r;
                        op[(long)d * 7500 + w] = acco[mi][ni][r];
                    }
                }
            }
    }
}

extern "C" void kernel_launch(void* const* d_in, const int* in_sizes, int n_in,
                              void* d_out, int out_size, void* d_ws, size_t ws_size,
                              hipStream_t stream) {
    const float* x = (const float*)d_in[0];
    const float* a = (const float*)d_in[1];
    const float* W = (const float*)d_in[2];
    const float* b = (const float*)d_in[3];
    float* out = (float*)d_out;
    // grid: 64 n * 25 t-chunks (12 t each); block: 4 waves
    hipLaunchKernelGGL(sgcn_fused, dim3(64 * 25), dim3(256), 0, stream,
                       x, a, W, b, out);
}

// Round 2
// 78.951 us; speedup vs baseline: 1.3216x; 1.3216x over previous
//
#include <hip/hip_runtime.h>

// SGCN fused: out[n,d,t,w] = sum_v (sum_c x[n,c,t,v]*W[c,d] + b[d]) * a[n,t,v,w]
// plus exact f32 copy of a into d_out second region.
// N=64, C_IN=C_OUT=64, T=300, V=25.
// Block = 4 waves, handles (n, t0..t0+3); wave wid computes t0+wid.
// Staging is block-cooperative, flat-indexed, float4-vectorized.

typedef __attribute__((ext_vector_type(8))) short short8;
typedef __attribute__((ext_vector_type(4))) float f32x4;

#define XS_S 66   // Wt/Xs row stride (ushort)
#define YS_S 36   // Ys row stride
#define AT_S 36   // At row stride

__device__ __forceinline__ unsigned short f2bf(float f) {
    unsigned int u = __builtin_bit_cast(unsigned int, f);
    return (unsigned short)((u + 0x7FFFu + ((u >> 16) & 1u)) >> 16);
}

__global__ __launch_bounds__(256, 3)
void sgcn_fused(const float* __restrict__ xg, const float* __restrict__ ag,
                const float* __restrict__ Wg, const float* __restrict__ bg,
                float* __restrict__ outg)
{
    __shared__ alignas(16) unsigned short Wt[64 * XS_S];      // W^T [d][c]
    __shared__ alignas(16) unsigned short Xs[4][32 * XS_S];   // x [t][v][c]
    __shared__ alignas(16) unsigned short Ys[4][64 * YS_S];   // y [t][d][v]
    __shared__ alignas(16) unsigned short At[4][32 * AT_S];   // a^T [t][w][v]

    const int tid  = threadIdx.x;
    const int wid  = tid >> 6;
    const int lane = tid & 63;
    const int q    = lane >> 4;   // 0..3
    const int lo   = lane & 15;   // 0..15

    const int bid = blockIdx.x;
    const int n   = bid / 75;
    const int t0  = (bid % 75) * 4;   // multiple of 4 -> 16B-aligned rows

    // ---------------- issue all global loads (independent, early) ----------
    // x slab: 64 c-rows x 100 floats (4 t's), flat index f: c=f/25, j=f%25
    f32x4 xv[7];
    const long xbase = ((long)n * 64 * 300 + t0) * 25;
#pragma unroll
    for (int m = 0; m < 7; ++m) {
        const int f = tid + 256 * m;
        if (m < 6 || f < 1600) {
            const int c = f / 25, j = f % 25;
            xv[m] = *(const f32x4*)(xg + xbase + (long)c * 7500 + 4 * j);
        }
    }
    // a slab: 2500 contiguous floats = 625 float4
    f32x4 av[3];
    const long abase = ((long)n * 300 + t0) * 625;
#pragma unroll
    for (int m = 0; m < 3; ++m) {
        const int f = tid + 256 * m;
        if (m < 2 || f < 625)
            av[m] = *(const f32x4*)(ag + abase + 4 * f);
    }
    // W: 4096 floats = 1024 float4
    f32x4 wv[4];
#pragma unroll
    for (int m = 0; m < 4; ++m)
        wv[m] = *(const f32x4*)(Wg + 4 * (tid + 256 * m));

    // ---------------- zero pad columns v=25..31 (K-dim of step 2) ----------
    {
        unsigned short* at = At[wid];
        unsigned short* ys = Ys[wid];
        if (lane < 32) {
#pragma unroll
            for (int i = 25; i < 32; ++i) at[lane * AT_S + i] = 0;
        }
#pragma unroll
        for (int i = 25; i < 32; ++i) ys[lane * YS_S + i] = 0;
    }

    // ---------------- scatter to LDS (bf16) --------------------------------
    // W -> Wt[d][c]   (Wg is [c][d])
#pragma unroll
    for (int m = 0; m < 4; ++m) {
        const int f = 4 * (tid + 256 * m);
#pragma unroll
        for (int i = 0; i < 4; ++i) {
            const int e = f + i, c = e >> 6, d = e & 63;
            Wt[d * XS_S + c] = f2bf(wv[m][i]);
        }
    }
    // x -> Xs[tl][v][c]
#pragma unroll
    for (int m = 0; m < 7; ++m) {
        const int f = tid + 256 * m;
        if (m < 6 || f < 1600) {
            const int c = f / 25, j = f % 25;
#pragma unroll
            for (int i = 0; i < 4; ++i) {
                const int e = 4 * j + i;          // 0..99 within the 4-t row
                const int tl = e / 25, v = e % 25;
                Xs[tl][v * XS_S + c] = f2bf(xv[m][i]);
            }
        }
    }
    // a -> f32 copy to out + At[tl][w][v]
    {
        float* aout = outg + 30720000L + abase;
#pragma unroll
        for (int m = 0; m < 3; ++m) {
            const int f = tid + 256 * m;
            if (m < 2 || f < 625) {
                *(f32x4*)(aout + 4 * f) = av[m];
#pragma unroll
                for (int i = 0; i < 4; ++i) {
                    const int e = 4 * f + i;       // (t,v,w) flat
                    const int tl = e / 625, r = e % 625;
                    At[tl][(r % 25) * AT_S + (r / 25)] = f2bf(av[m][i]);
                }
            }
        }
    }
    __syncthreads();

    // ---------------- per-wave compute for t = t0 + wid --------------------
    // W A-fragments + bias
    short8 wfrag[4][2];
#pragma unroll
    for (int mi = 0; mi < 4; ++mi)
#pragma unroll
        for (int ki = 0; ki < 2; ++ki)
            wfrag[mi][ki] = *(const short8*)&Wt[(16 * mi + lo) * XS_S + 32 * ki + 8 * q];

    f32x4 bias[4];
#pragma unroll
    for (int mi = 0; mi < 4; ++mi)
#pragma unroll
        for (int r = 0; r < 4; ++r)
            bias[mi][r] = bg[16 * mi + 4 * q + r];

    unsigned short* xs = Xs[wid];
    unsigned short* ys = Ys[wid];
    unsigned short* at = At[wid];
    const int t = t0 + wid;

    // step 1: y[d,v] = b[d] + sum_c W[c,d] x[c,v]   (M=64, N=32pad, K=64)
    f32x4 accy[4][2];
#pragma unroll
    for (int mi = 0; mi < 4; ++mi) { accy[mi][0] = bias[mi]; accy[mi][1] = bias[mi]; }
#pragma unroll
    for (int ni = 0; ni < 2; ++ni)
#pragma unroll
        for (int ki = 0; ki < 2; ++ki) {
            const short8 bf = *(const short8*)&xs[(16 * ni + lo) * XS_S + 32 * ki + 8 * q];
#pragma unroll
            for (int mi = 0; mi < 4; ++mi)
                accy[mi][ni] = __builtin_amdgcn_mfma_f32_16x16x32_bf16(
                    wfrag[mi][ki], bf, accy[mi][ni], 0, 0, 0);
        }

    // y -> Ys[d][v] (bf16), D layout: lane holds D[4q+r][lo]
#pragma unroll
    for (int mi = 0; mi < 4; ++mi)
#pragma unroll
        for (int ni = 0; ni < 2; ++ni) {
            const int v = 16 * ni + lo;
            if (v < 25) {
#pragma unroll
                for (int r = 0; r < 4; ++r)
                    ys[(16 * mi + 4 * q + r) * YS_S + v] = f2bf(accy[mi][ni][r]);
            }
        }

    // step 2 (swapped): O^T[w,d] = sum_v a^T[w,v] * y^T[v,d]
    //   A-frag from At[w][v], B-frag from Ys[d][v]; M=32pad(w), N=64(d), K=32pad(v)
    short8 afr[2];
#pragma unroll
    for (int mi = 0; mi < 2; ++mi)
        afr[mi] = *(const short8*)&at[(16 * mi + lo) * AT_S + 8 * q];
    short8 yfr[4];
#pragma unroll
    for (int dj = 0; dj < 4; ++dj)
        yfr[dj] = *(const short8*)&ys[(16 * dj + lo) * YS_S + 8 * q];

    f32x4 acco[2][4];
#pragma unroll
    for (int mi = 0; mi < 2; ++mi)
#pragma unroll
        for (int dj = 0; dj < 4; ++dj)
            acco[mi][dj] = f32x4{0.f, 0.f, 0.f, 0.f};
#pragma unroll
    for (int mi = 0; mi < 2; ++mi)
#pragma unroll
        for (int dj = 0; dj < 4; ++dj)
            acco[mi][dj] = __builtin_amdgcn_mfma_f32_16x16x32_bf16(
                afr[mi], yfr[dj], acco[mi][dj], 0, 0, 0);

    // store: D[row = w = 16mi+4q+r][col = d = 16dj+lo] -> out[n,d,t,w]
    // lane's 4 regs are CONSECUTIVE w -> float4 stores (dword-aligned OK on CDNA)
    float* op = outg + ((long)n * 64 * 300 + t) * 25;
#pragma unroll
    for (int dj = 0; dj < 4; ++dj) {
        const long dbase = (long)(16 * dj + lo) * 7500;
        *(f32x4*)(op + dbase + 4 * q) = acco[0][dj];          // w = 4q+0..3  (<16)
        if (q < 2)
            *(f32x4*)(op + dbase + 16 + 4 * q) = acco[1][dj]; // w = 16..23
        else if (q == 2)
            op[dbase + 24] = acco[1][dj][0];                  // w = 24
    }
}

extern "C" void kernel_launch(void* const* d_in, const int* in_sizes, int n_in,
                              void* d_out, int out_size, void* d_ws, size_t ws_size,
                              hipStream_t stream) {
    const float* x = (const float*)d_in[0];
    const float* a = (const float*)d_in[1];
    const float* W = (const float*)d_in[2];
    const float* b = (const float*)d_in[3];
    float* out = (float*)d_out;
    hipLaunchKernelGGL(sgcn_fused, dim3(64 * 75), dim3(256), 0, stream,
                       x, a, W, b, out);
}

// Round 3
// 76.896 us; speedup vs baseline: 1.3569x; 1.0267x over previous
//
#include <hip/hip_runtime.h>

// SGCN fused: out[n,d,t,w] = sum_v (sum_c x[n,c,t,v]*W[c,d] + b[d]) * a[n,t,v,w]
// plus exact f32 copy of a into d_out second region.
// N=64, C_IN=C_OUT=64, T=300, V=25.
// Block = 512 threads (8 waves), handles (n, t0..t0+3).
// Wave wid: tl = wid>>1 (which t), dh = wid&1 (which 32-row d-half).
// Per-wave Ys is private (step-2 B-frags come from the wave's own y-half).

typedef __attribute__((ext_vector_type(8))) short short8;
typedef __attribute__((ext_vector_type(4))) float f32x4;

#define XS_S 66   // Wt/Xs row stride (ushort)
#define YS_S 36   // Ys row stride
#define AT_S 36   // At row stride

__device__ __forceinline__ unsigned short f2bf(float f) {
    unsigned int u = __builtin_bit_cast(unsigned int, f);
    return (unsigned short)((u + 0x7FFFu + ((u >> 16) & 1u)) >> 16);
}

__global__ __launch_bounds__(512, 6)
void sgcn_fused(const float* __restrict__ xg, const float* __restrict__ ag,
                const float* __restrict__ Wg, const float* __restrict__ bg,
                float* __restrict__ outg)
{
    __shared__ alignas(16) unsigned short Wt[64 * XS_S];      // W^T [d][c]
    __shared__ alignas(16) unsigned short Xs[4][32 * XS_S];   // x [tl][v][c]
    __shared__ alignas(16) unsigned short Ys[8][32 * YS_S];   // y [wave][dlocal][v]
    __shared__ alignas(16) unsigned short At[4][32 * AT_S];   // a^T [tl][w][v]

    const int tid  = threadIdx.x;
    const int wid  = tid >> 6;
    const int lane = tid & 63;
    const int q    = lane >> 4;   // 0..3
    const int lo   = lane & 15;   // 0..15

    const int bid = blockIdx.x;
    const int n   = bid / 75;
    const int t0  = (bid % 75) * 4;

    // ---------------- issue all global loads (independent, early) ----------
    // x slab: 64 c-rows x 100 floats (4 t's) = 1600 float4
    f32x4 xv[4];
    const long xbase = ((long)n * 64 * 300 + t0) * 25;
#pragma unroll
    for (int m = 0; m < 4; ++m) {
        const int f = tid + 512 * m;
        if (m < 3 || f < 1600) {
            const int c = f / 25, j = f % 25;
            xv[m] = *(const f32x4*)(xg + xbase + (long)c * 7500 + 4 * j);
        }
    }
    // a slab: 2500 floats = 625 float4
    f32x4 av[2];
    const long abase = ((long)n * 300 + t0) * 625;
#pragma unroll
    for (int m = 0; m < 2; ++m) {
        const int f = tid + 512 * m;
        if (m < 1 || f < 625)
            av[m] = *(const f32x4*)(ag + abase + 4 * f);
    }
    // W: 4096 floats = 1024 float4
    f32x4 wv[2];
#pragma unroll
    for (int m = 0; m < 2; ++m)
        wv[m] = *(const f32x4*)(Wg + 4 * (tid + 512 * m));

    // ---------------- zero pad columns v=25..31 (K-dim of step 2) ----------
    if (tid < 256) {   // Ys: 8 waves * 32 rows
        unsigned short* yr = &Ys[tid >> 5][(tid & 31) * YS_S];
#pragma unroll
        for (int i = 25; i < 32; ++i) yr[i] = 0;
    } else if (tid < 384) {  // At: 4 tl * 32 rows
        const int r = tid - 256;
        unsigned short* ar = &At[r >> 5][(r & 31) * AT_S];
#pragma unroll
        for (int i = 25; i < 32; ++i) ar[i] = 0;
    }

    // ---------------- scatter to LDS (bf16) --------------------------------
    // W -> Wt[d][c]
#pragma unroll
    for (int m = 0; m < 2; ++m) {
        const int f = 4 * (tid + 512 * m);
#pragma unroll
        for (int i = 0; i < 4; ++i) {
            const int e = f + i, c = e >> 6, d = e & 63;
            Wt[d * XS_S + c] = f2bf(wv[m][i]);
        }
    }
    // x -> Xs[tl][v][c]
#pragma unroll
    for (int m = 0; m < 4; ++m) {
        const int f = tid + 512 * m;
        if (m < 3 || f < 1600) {
            const int c = f / 25, j = f % 25;
#pragma unroll
            for (int i = 0; i < 4; ++i) {
                const int e = 4 * j + i;          // 0..99 within the 4-t row
                const int tl = e / 25, v = e % 25;
                Xs[tl][v * XS_S + c] = f2bf(xv[m][i]);
            }
        }
    }
    // a -> f32 copy to out + At[tl][w][v]
    {
        float* aout = outg + 30720000L + abase;
#pragma unroll
        for (int m = 0; m < 2; ++m) {
            const int f = tid + 512 * m;
            if (m < 1 || f < 625) {
                *(f32x4*)(aout + 4 * f) = av[m];
#pragma unroll
                for (int i = 0; i < 4; ++i) {
                    const int e = 4 * f + i;       // (t,v,w) flat
                    const int tl = e / 625, r = e % 625;
                    At[tl][(r % 25) * AT_S + (r / 25)] = f2bf(av[m][i]);
                }
            }
        }
    }
    __syncthreads();

    // ---------------- per-wave compute: t = t0 + tl, d in [32*dh, 32*dh+32) -
    const int tl = wid >> 1;
    const int dh = wid & 1;
    const int t  = t0 + tl;
    const int d0 = 32 * dh;

    short8 wfrag[2][2];
#pragma unroll
    for (int mi = 0; mi < 2; ++mi)
#pragma unroll
        for (int ki = 0; ki < 2; ++ki)
            wfrag[mi][ki] = *(const short8*)&Wt[(d0 + 16 * mi + lo) * XS_S + 32 * ki + 8 * q];

    f32x4 bias[2];
#pragma unroll
    for (int mi = 0; mi < 2; ++mi)
#pragma unroll
        for (int r = 0; r < 4; ++r)
            bias[mi][r] = bg[d0 + 16 * mi + 4 * q + r];

    unsigned short* xs = Xs[tl];
    unsigned short* ys = Ys[wid];
    unsigned short* at = At[tl];

    // step 1: y[dlocal,v] = b + sum_c W[c,d] x[c,v]   (M=32, N=32pad, K=64)
    f32x4 accy[2][2];
#pragma unroll
    for (int mi = 0; mi < 2; ++mi) { accy[mi][0] = bias[mi]; accy[mi][1] = bias[mi]; }
#pragma unroll
    for (int ni = 0; ni < 2; ++ni)
#pragma unroll
        for (int ki = 0; ki < 2; ++ki) {
            const short8 bf = *(const short8*)&xs[(16 * ni + lo) * XS_S + 32 * ki + 8 * q];
#pragma unroll
            for (int mi = 0; mi < 2; ++mi)
                accy[mi][ni] = __builtin_amdgcn_mfma_f32_16x16x32_bf16(
                    wfrag[mi][ki], bf, accy[mi][ni], 0, 0, 0);
        }

    // y -> Ys[dlocal][v] (bf16); D layout: lane holds D[16mi+4q+r][16ni+lo]
#pragma unroll
    for (int mi = 0; mi < 2; ++mi)
#pragma unroll
        for (int ni = 0; ni < 2; ++ni) {
            const int v = 16 * ni + lo;
            if (v < 25) {
#pragma unroll
                for (int r = 0; r < 4; ++r)
                    ys[(16 * mi + 4 * q + r) * YS_S + v] = f2bf(accy[mi][ni][r]);
            }
        }

    // step 2 (swapped): O^T[w, dlocal] = sum_v a^T[w,v] * y[dlocal,v]^T
    short8 afr[2];
#pragma unroll
    for (int mi = 0; mi < 2; ++mi)
        afr[mi] = *(const short8*)&at[(16 * mi + lo) * AT_S + 8 * q];
    short8 yfr[2];
#pragma unroll
    for (int dj = 0; dj < 2; ++dj)
        yfr[dj] = *(const short8*)&ys[(16 * dj + lo) * YS_S + 8 * q];

    f32x4 acco[2][2];
#pragma unroll
    for (int mi = 0; mi < 2; ++mi)
#pragma unroll
        for (int dj = 0; dj < 2; ++dj)
            acco[mi][dj] = f32x4{0.f, 0.f, 0.f, 0.f};
#pragma unroll
    for (int mi = 0; mi < 2; ++mi)
#pragma unroll
        for (int dj = 0; dj < 2; ++dj)
            acco[mi][dj] = __builtin_amdgcn_mfma_f32_16x16x32_bf16(
                afr[mi], yfr[dj], acco[mi][dj], 0, 0, 0);

    // store: D[row = w = 16mi+4q+r][col = dlocal = 16dj+lo] -> out[n, d, t, w]
    float* op = outg + ((long)n * 64 * 300 + t) * 25;
#pragma unroll
    for (int dj = 0; dj < 2; ++dj) {
        const long dbase = (long)(d0 + 16 * dj + lo) * 7500;
        *(f32x4*)(op + dbase + 4 * q) = acco[0][dj];          // w = 4q..4q+3
        if (q < 2)
            *(f32x4*)(op + dbase + 16 + 4 * q) = acco[1][dj]; // w = 16..23
        else if (q == 2)
            op[dbase + 24] = acco[1][dj][0];                  // w = 24
    }
}

extern "C" void kernel_launch(void* const* d_in, const int* in_sizes, int n_in,
                              void* d_out, int out_size, void* d_ws, size_t ws_size,
                              hipStream_t stream) {
    const float* x = (const float*)d_in[0];
    const float* a = (const float*)d_in[1];
    const float* W = (const float*)d_in[2];
    const float* b = (const float*)d_in[3];
    float* out = (float*)d_out;
    hipLaunchKernelGGL(sgcn_fused, dim3(64 * 75), dim3(512), 0, stream,
                       x, a, W, b, out);
}